// Round 14
// baseline (123.446 us; speedup 1.0000x reference)
//
#include <hip/hip_runtime.h>
#include <hip/hip_bf16.h>

typedef __attribute__((ext_vector_type(8))) __bf16 bf16x8;
typedef __attribute__((ext_vector_type(4))) __bf16 bf16x4;
typedef __attribute__((ext_vector_type(4))) float  f32x4;

#define MFMA16(a, b, c) __builtin_amdgcn_mfma_f32_16x16x32_bf16((a), (b), (c), 0, 0, 0)

// B=2, S=4096, D=256, P=R=64. Flattened rows g = b*4096 + n (8192 total).
// Wo folded into Wv: Wvo = Wv @ Wo -> attention partials are pre-scale output.
// x pre-converted to bf16 once in k_prepw.
static constexpr size_t OFF_WVT  = 0;                        // bf16 [256][256] (Wvo^T, [n][k])
static constexpr size_t OFF_WLT  = OFF_WVT + 256 * 256 * 2;  // bf16 [64][256]
static constexpr size_t OFF_WRT  = OFF_WLT + 64 * 256 * 2;   // bf16 [64][256]
static constexpr size_t OFF_VT   = 1u << 20;                 // bf16 [2][64][8][256][8] packed V', 4 MiB
static constexpr size_t OFF_L    = 6u << 20;                 // f32  [8192][64]  2 MiB
static constexpr size_t OFF_R    = 8u << 20;                 // f32  [8192][64]  2 MiB
static constexpr size_t OFF_PART = 10u << 20;                // bf16 [4][8192][256] 16 MiB
static constexpr size_t OFF_ZP   = 26u << 20;                // f32  [4][8192]   128 KiB
static constexpr size_t OFF_XB   = 27u << 20;                // bf16 [8192][256] 4 MiB

__device__ __forceinline__ float fast_exp2(float x) {
  float e;
  asm("v_exp_f32 %0, %1" : "=v"(e) : "v"(x));
  return e;
}

__device__ __forceinline__ bf16x8 cvt8(float4 a, float4 b) {
  bf16x8 o;
  o[0] = (__bf16)a.x; o[1] = (__bf16)a.y; o[2] = (__bf16)a.z; o[3] = (__bf16)a.w;
  o[4] = (__bf16)b.x; o[5] = (__bf16)b.y; o[6] = (__bf16)b.z; o[7] = (__bf16)b.w;
  return o;
}

// async global->LDS, 16B/lane; lds dst is the wave-uniform base (HW adds 16*lane).
__device__ __forceinline__ void gll16(const __bf16* g, __bf16* l) {
  __builtin_amdgcn_global_load_lds((const __attribute__((address_space(1))) void*)g,
                                   (__attribute__((address_space(3))) void*)l,
                                   16, 0, 0);
}

// ---------------- weight prep + x->bf16 (R13 version, verbatim)
__global__ __launch_bounds__(1024) void k_prepw(const float* __restrict__ Wv,
                                                const float* __restrict__ Wl,
                                                const float* __restrict__ Wr,
                                                const float* __restrict__ Wo,
                                                const float* __restrict__ x,
                                                __bf16* __restrict__ Wvt,
                                                __bf16* __restrict__ Wlt,
                                                __bf16* __restrict__ Wrt,
                                                __bf16* __restrict__ xb) {
  __shared__ float red[3][256];
  const int blk = blockIdx.x;
  const int t = threadIdx.x;
  if (blk < 32) {
    const int idx = blk * 1024 + t;              // 0 .. 32767
    if (idx < 16384) {
      const int k = idx >> 6, n = idx & 63;
      Wlt[n * 256 + k] = (__bf16)Wl[idx];
    } else {
      const int j = idx - 16384;
      const int k = j >> 6, n = j & 63;
      Wrt[n * 256 + k] = (__bf16)Wr[j];
    }
  } else if (blk < 288) {
    const int k  = blk - 32;                     // 0..255
    const int n  = t & 255;
    const int jq = t >> 8;                       // 0..3
    const float* wvr = Wv + (size_t)k * 256 + jq * 64;
    const float* wor = Wo + (size_t)(jq * 64) * 256 + n;
    float a0 = 0.f, a1 = 0.f, a2 = 0.f, a3 = 0.f;
#pragma unroll 4
    for (int j = 0; j < 64; j += 4) {
      a0 += wvr[j + 0] * wor[(size_t)(j + 0) * 256];
      a1 += wvr[j + 1] * wor[(size_t)(j + 1) * 256];
      a2 += wvr[j + 2] * wor[(size_t)(j + 2) * 256];
      a3 += wvr[j + 3] * wor[(size_t)(j + 3) * 256];
    }
    const float s = (a0 + a1) + (a2 + a3);
    if (jq > 0) red[jq - 1][n] = s;
    __syncthreads();
    if (jq == 0)
      Wvt[(size_t)n * 256 + k] = (__bf16)(s + red[0][n] + red[1][n] + red[2][n]);
  } else {
    const size_t base = (size_t)(blk - 288) * 8192 + (size_t)t * 8;
    float4 a = *(const float4*)(x + base);
    float4 b = *(const float4*)(x + base + 4);
    *(bf16x8*)(xb + base) = cvt8(a, b);
  }
}

// --------- projections (R13 version, verbatim): bf16 xb A-operands.
__global__ __launch_bounds__(256) void k_proj(const __bf16* __restrict__ xb,
                                              const __bf16* __restrict__ Wvt,
                                              const __bf16* __restrict__ Wlt,
                                              const __bf16* __restrict__ Wrt,
                                              __bf16* __restrict__ Vt,
                                              float* __restrict__ lbuf,
                                              float* __restrict__ rbuf) {
  __shared__ __align__(16) char smem[16896];       // V path: 8KB bf16; lr path: [64][65] f32
  const int t = threadIdx.x;
  const int lane = t & 63, wave = t >> 6;
  const int l16 = lane & 15, quad = lane >> 4;
  const int wr = wave >> 1, wc = wave & 1;
  const int bid = blockIdx.x;
  const int q   = bid / 48;
  const int rmd = bid - q * 48;
  const int ct  = rmd >> 3;
  const int rbk = q * 8 + (rmd & 7);
  const __bf16* Wt;
  int colbase;
  if (ct < 4)       { Wt = Wvt; colbase = ct * 64; }
  else if (ct == 4) { Wt = Wlt; colbase = 0; }
  else              { Wt = Wrt; colbase = 0; }
  const int row0 = rbk * 64 + wr * 32;
  const int c0   = colbase + wc * 32;
  f32x4 acc[2][2] = {};
  for (int kk = 0; kk < 256; kk += 32) {
    const int ko = kk + quad * 8;
    bf16x8 a0 = *(const bf16x8*)(xb + (size_t)(row0 + l16) * 256 + ko);
    bf16x8 a1 = *(const bf16x8*)(xb + (size_t)(row0 + 16 + l16) * 256 + ko);
    bf16x8 b0 = *(const bf16x8*)(Wt + (size_t)(c0 + l16) * 256 + ko);
    bf16x8 b1 = *(const bf16x8*)(Wt + (size_t)(c0 + 16 + l16) * 256 + ko);
    acc[0][0] = MFMA16(a0, b0, acc[0][0]);
    acc[0][1] = MFMA16(a0, b1, acc[0][1]);
    acc[1][0] = MFMA16(a1, b0, acc[1][0]);
    acc[1][1] = MFMA16(a1, b1, acc[1][1]);
  }
  if (ct < 4) {
    __bf16* vs = (__bf16*)smem;                  // [m8][d_local][j]
#pragma unroll
    for (int mt = 0; mt < 2; ++mt)
#pragma unroll
      for (int nt = 0; nt < 2; ++nt) {
        const int m8 = wr * 4 + mt * 2 + (quad >> 1);
        const int d  = wc * 32 + nt * 16 + l16;
        bf16x4 o;
        o.x = (__bf16)acc[mt][nt][0];
        o.y = (__bf16)acc[mt][nt][1];
        o.z = (__bf16)acc[mt][nt][2];
        o.w = (__bf16)acc[mt][nt][3];
        *(bf16x4*)(&vs[m8 * 512 + d * 8 + (quad & 1) * 4]) = o;
      }
    __syncthreads();
    const int m8 = t >> 5, s32 = t & 31;
    const int bat = rbk >> 6, mc = rbk & 63;
    bf16x8 a = *(const bf16x8*)(&vs[m8 * 512 + s32 * 16]);
    bf16x8 b = *(const bf16x8*)(&vs[m8 * 512 + s32 * 16 + 8]);
    __bf16* dst = Vt + (size_t)bat * 1048576 + (size_t)mc * 16384 +
                  m8 * 2048 + ct * 512 + s32 * 16;
    *(bf16x8*)dst       = a;
    *(bf16x8*)(dst + 8) = b;
  } else {
    float* lsf = (float*)smem;                   // [64][65]
#pragma unroll
    for (int mt = 0; mt < 2; ++mt)
#pragma unroll
      for (int nt = 0; nt < 2; ++nt) {
        const int col = wc * 32 + nt * 16 + l16;
        const int r0  = wr * 32 + mt * 16 + quad * 4;
#pragma unroll
        for (int rr = 0; rr < 4; ++rr)
          lsf[(r0 + rr) * 65 + col] = acc[mt][nt][rr];
      }
    __syncthreads();
    float* dstb = (ct == 4) ? lbuf : rbuf;
    const int row = t >> 2, cs = (t & 3) * 16;
    const float* src = lsf + row * 65 + cs;
    float* d = dstb + (size_t)(rbk * 64 + row) * 64 + cs;
#pragma unroll
    for (int v = 0; v < 4; ++v) {
      f32x4 o;
      o[0] = src[v * 4 + 0]; o[1] = src[v * 4 + 1];
      o[2] = src[v * 4 + 2]; o[3] = src[v * 4 + 3];
      *(f32x4*)(d + v * 4) = o;
    }
  }
}

// ---------------- main attention GEMM: occupancy via smaller natural state.
// grid 1024 x 256thr: TM=64, TN=128, split-K=4 (32 chunks of K=32, same
// K-span as R6). acc[2][4]=32 VGPR (was 64), LDS 36.3 KB (4x8KB vb + ls)
// -> FOUR blocks/CU = 4 waves/SIMD naturally (no launch-bounds forcing;
// (256,2) is only a spill guard). Doubles TLP overlap of the measured
// multi-resource stack (trans-pipe exp + L2 V-reads + barriers + issue)
// that pinned R6's attn at 27us with 2 waves/SIMD.
// Same counted-vmcnt pipeline; 2 loads/chunk, depth 3 -> vmcnt(6), tail 6/4/2/0.
// bid&7 -> (sp,bat) keeps each XCD on one 512KB V-split (both ch-halves).
__global__ __launch_bounds__(256, 2) void k_attn(const float* __restrict__ lbuf,
                                                 const float* __restrict__ rbuf,
                                                 const __bf16* __restrict__ Vt,
                                                 __bf16* __restrict__ part,
                                                 float* __restrict__ zpart) {
  __shared__ __align__(16) char smem[37120];   // vb[4][8KB] + ls[64][17]f32; epi ctile aliases
  __bf16* vb0 = (__bf16*)smem;
  __bf16* vb1 = (__bf16*)(smem + 8192);
  __bf16* vb2 = (__bf16*)(smem + 16384);
  __bf16* vb3 = (__bf16*)(smem + 24576);
  float*  ls  = (float*)(smem + 32768);        // [64][17]
  const int t = threadIdx.x;                   // 0..255
  const int lane = t & 63, w = t >> 6;
  const int l16 = lane & 15, quad = lane >> 4;
  const int wr = w >> 1, wc = w & 1;           // 2 row-waves x 2 col-waves
  const int bid = blockIdx.x;                  // 0..1023
  const int cmb = bid & 7;
  const int sp  = cmb >> 1;                    // 0..3
  const int bat = cmb & 1;                     // 0..1
  const int ch  = (bid >> 3) & 1;              // col half 0..1
  const int rbl = bid >> 4;                    // 0..63
  const int g0  = bat * 4096 + rbl * 64;
  const __bf16* Vbase = Vt + (size_t)bat * 1048576;
  const int ck0 = sp * 32;                     // first K=32 chunk of this split

  // l tile: rows g0..+63, 16 chunk-cols (stride 17 -> conflict-free reads)
  {
    const int row = t >> 2, c = (t & 3) * 4;
    f32x4 v = *(const f32x4*)(lbuf + (size_t)(g0 + row) * 64 + sp * 16 + c);
    ls[row * 17 + c + 0] = v[0];
    ls[row * 17 + c + 1] = v[1];
    ls[row * 17 + c + 2] = v[2];
    ls[row * 17 + c + 3] = v[3];
  }
  // r fragments pre-scaled by log2(e)
  const float LOG2E = 1.44269504088896f;
  float rreg[2][16];
#pragma unroll
  for (int mt = 0; mt < 2; ++mt) {
    const float* rp = rbuf + (size_t)(g0 + wr * 32 + mt * 16 + l16) * 64;
    f32x4 a = *(const f32x4*)(rp + quad * 8);
    f32x4 b = *(const f32x4*)(rp + quad * 8 + 4);
    f32x4 c = *(const f32x4*)(rp + 32 + quad * 8);
    f32x4 d = *(const f32x4*)(rp + 32 + quad * 8 + 4);
#pragma unroll
    for (int j = 0; j < 4; ++j) {
      rreg[mt][j]      = a[j] * LOG2E;
      rreg[mt][4 + j]  = b[j] * LOG2E;
      rreg[mt][8 + j]  = c[j] * LOG2E;
      rreg[mt][12 + j] = d[j] * LOG2E;
    }
  }

  f32x4 acc[2][4] = {};
  float zacc[2][2] = {{0.f, 0.f}, {0.f, 0.f}};

  // stage the block's 128-col window of K=32 chunk KC (8 KB): 2 gll16/thread.
  // global elem = kc*8192 + m8l*2048 + ch*1024 + dlocal*8; LDS linear [m8l][dlocal][j].
#define STAGE(KC, DST)                                                        \
  {                                                                           \
    const __bf16* src = Vbase + (size_t)(ck0 + (KC)) * 8192 + ch * 1024;      \
    _Pragma("unroll")                                                         \
    for (int i = 0; i < 2; ++i) {                                             \
      const int unit = i * 256 + t;                                           \
      gll16(src + (size_t)(unit >> 7) * 2048 + (unit & 127) * 8,              \
            (DST) + (i * 256 + (w << 6)) * 8);                                \
    }                                                                         \
  }

#define AF_COMPUTE(KC)                                                        \
  {                                                                           \
    const int c16 = (KC) >> 1, hf = ((KC) & 1) * 8;                           \
    _Pragma("unroll")                                                         \
    for (int mt = 0; mt < 2; ++mt) {                                          \
      const float lv = ls[(wr * 32 + mt * 16 + l16) * 17 + c16];              \
      _Pragma("unroll")                                                       \
      for (int j = 0; j < 8; ++j) {                                           \
        const float e = fast_exp2(lv * rreg[mt][hf + j]);                     \
        zacc[mt][(KC) & 1] += e;                                              \
        af[mt][j] = (__bf16)e;                                                \
      }                                                                       \
    }                                                                         \
  }

  // 4 ds_read_b128 + 8 MFMA; buffer = [m8l=quad][dlocal 128][j 8]
#define MFMA_PHASE(CUR)                                                       \
  {                                                                           \
    _Pragma("unroll")                                                         \
    for (int nt = 0; nt < 4; ++nt) {                                          \
      bf16x8 bv = *(const bf16x8*)((CUR) + quad * 1024 +                      \
                                   (wc * 64 + nt * 16 + l16) * 8);            \
      acc[0][nt] = MFMA16(af[0], bv, acc[0][nt]);                             \
      acc[1][nt] = MFMA16(af[1], bv, acc[1][nt]);                             \
    }                                                                         \
  }

#define STEP(CC, BCUR, SC, BST, VM)                                           \
  {                                                                           \
    STAGE(SC, BST);                                                           \
    bf16x8 af[2];                                                             \
    AF_COMPUTE(CC);                                                           \
    asm volatile("s_waitcnt vmcnt(" #VM ")" ::: "memory");                    \
    __builtin_amdgcn_s_barrier();                                             \
    __builtin_amdgcn_sched_barrier(0);                                        \
    MFMA_PHASE(BCUR);                                                         \
    __builtin_amdgcn_s_barrier();                                             \
    __builtin_amdgcn_sched_barrier(0);                                        \
  }

#define STEPX(CC, BCUR, VM)                                                   \
  {                                                                           \
    bf16x8 af[2];                                                             \
    AF_COMPUTE(CC);                                                           \
    asm volatile("s_waitcnt vmcnt(" #VM ")" ::: "memory");                    \
    __builtin_amdgcn_s_barrier();                                             \
    __builtin_amdgcn_sched_barrier(0);                                        \
    MFMA_PHASE(BCUR);                                                         \
    __builtin_amdgcn_s_barrier();                                             \
    __builtin_amdgcn_sched_barrier(0);                                        \
  }

  // prologue: chunks 0..2 staged; the only full drain in the loop
  STAGE(0, vb0);
  STAGE(1, vb1);
  STAGE(2, vb2);
  __syncthreads();

  // steady: chunk cc in buffer cc%4; depth 3, 2 loads/chunk -> vmcnt(6)
  for (int c = 0; c < 28; c += 4) {
    STEP(c + 0, vb0, c + 3, vb3, 6);
    STEP(c + 1, vb1, c + 4, vb0, 6);
    STEP(c + 2, vb2, c + 5, vb1, 6);
    STEP(c + 3, vb3, c + 6, vb2, 6);
  }
  STEP (28, vb0, 31, vb3, 6);
  STEPX(29, vb1, 4);
  STEPX(30, vb2, 2);
  STEPX(31, vb3, 0);

#undef STAGE
#undef AF_COMPUTE
#undef MFMA_PHASE
#undef STEP
#undef STEPX

  // Z partials (identical across ch and col-waves; ch==0/wc==0 owns the write)
#pragma unroll
  for (int mt = 0; mt < 2; ++mt) {
    float z = zacc[mt][0] + zacc[mt][1];
    z += __shfl_xor(z, 16);
    z += __shfl_xor(z, 32);
    if (ch == 0 && wc == 0 && quad == 0)
      zpart[(size_t)sp * 8192 + g0 + wr * 32 + mt * 16 + l16] = z;
  }

  // epilogue: stage C tile (64x128 bf16, stride 136 = 17.4 KB) in LDS
  __syncthreads();                 // all LDS reads done before aliasing
  __bf16* ctile = (__bf16*)smem;
#pragma unroll
  for (int mt = 0; mt < 2; ++mt)
#pragma unroll
    for (int nt = 0; nt < 4; ++nt) {
      const int r0 = wr * 32 + mt * 16 + quad * 4;
      const int c  = wc * 64 + nt * 16 + l16;
#pragma unroll
      for (int rr = 0; rr < 4; ++rr)
        ctile[(r0 + rr) * 136 + c] = (__bf16)acc[mt][nt][rr];
    }
  __syncthreads();
  __bf16* pb = part + (size_t)sp * (8192 * 256) + ch * 128;
#pragma unroll
  for (int p = 0; p < 4; ++p) {
    const int u = p * 256 + t;
    const int row = u >> 4, seg = u & 15;
    *(bf16x8*)(pb + (size_t)(g0 + row) * 256 + seg * 8) =
        *(const bf16x8*)(ctile + row * 136 + seg * 8);
  }
}

// ------- final fixup (R6 version): out = (sum_s part[s]) / Z  (pure streaming)
__global__ __launch_bounds__(256) void k_fix(const __bf16* __restrict__ part,
                                             const float* __restrict__ zpart,
                                             float* __restrict__ out) {
  const int idx = blockIdx.x * 256 + threadIdx.x;   // 0 .. 262143
  const int g = idx >> 5, seg = idx & 31;
  float z = 0.f;
#pragma unroll
  for (int s = 0; s < 4; ++s) z += zpart[(size_t)s * 8192 + g];
  const float iz = 1.0f / z;
  float sum[8] = {};
#pragma unroll
  for (int s = 0; s < 4; ++s) {
    bf16x8 p = *(const bf16x8*)(part + (size_t)s * (8192 * 256) + (size_t)g * 256 + seg * 8);
#pragma unroll
    for (int j = 0; j < 8; ++j) sum[j] += (float)p[j];
  }
  f32x4 o0, o1;
#pragma unroll
  for (int j = 0; j < 4; ++j) { o0[j] = sum[j] * iz; o1[j] = sum[4 + j] * iz; }
  float* dst = out + (size_t)g * 256 + seg * 8;
  *(f32x4*)dst       = o0;
  *(f32x4*)(dst + 4) = o1;
}

extern "C" void kernel_launch(void* const* d_in, const int* in_sizes, int n_in,
                              void* d_out, int out_size, void* d_ws, size_t ws_size,
                              hipStream_t stream) {
  const float* x  = (const float*)d_in[0];
  const float* Wl = (const float*)d_in[1];
  const float* Wr = (const float*)d_in[2];
  const float* Wv = (const float*)d_in[3];
  const float* Wo = (const float*)d_in[4];
  char* ws = (char*)d_ws;
  __bf16* Wvt = (__bf16*)(ws + OFF_WVT);
  __bf16* Wlt = (__bf16*)(ws + OFF_WLT);
  __bf16* Wrt = (__bf16*)(ws + OFF_WRT);
  __bf16* Vt  = (__bf16*)(ws + OFF_VT);
  float*  lb  = (float*)(ws + OFF_L);
  float*  rbf = (float*)(ws + OFF_R);
  __bf16* prt = (__bf16*)(ws + OFF_PART);
  float*  zp  = (float*)(ws + OFF_ZP);
  __bf16* xb  = (__bf16*)(ws + OFF_XB);
  float*  out = (float*)d_out;

  k_prepw<<<544, 1024, 0, stream>>>(Wv, Wl, Wr, Wo, x, Wvt, Wlt, Wrt, xb);
  k_proj<<<768, 256, 0, stream>>>(xb, Wvt, Wlt, Wrt, Vt, lb, rbf);
  k_attn<<<1024, 256, 0, stream>>>(lb, rbf, Vt, prt, zp);
  k_fix<<<1024, 256, 0, stream>>>(prt, zp, out);
}

// Round 15
// 114.628 us; speedup vs baseline: 1.0769x; 1.0769x over previous
//
#include <hip/hip_runtime.h>
#include <hip/hip_bf16.h>

typedef __attribute__((ext_vector_type(8))) __bf16 bf16x8;
typedef __attribute__((ext_vector_type(4))) __bf16 bf16x4;
typedef __attribute__((ext_vector_type(4))) float  f32x4;

#define MFMA16(a, b, c) __builtin_amdgcn_mfma_f32_16x16x32_bf16((a), (b), (c), 0, 0, 0)

// B=2, S=4096, D=256, P=R=64. Flattened rows g = b*4096 + n (8192 total).
// Wo folded into Wv: Wvo = Wv @ Wo -> attention partials are pre-scale output.
// x pre-converted to bf16 once in k_prepw.
static constexpr size_t OFF_WVT  = 0;                        // bf16 [256][256] (Wvo^T, [n][k])
static constexpr size_t OFF_WLT  = OFF_WVT + 256 * 256 * 2;  // bf16 [64][256]
static constexpr size_t OFF_WRT  = OFF_WLT + 64 * 256 * 2;   // bf16 [64][256]
static constexpr size_t OFF_VT   = 1u << 20;                 // bf16 [2][64][8][256][8] packed V', 4 MiB
static constexpr size_t OFF_L    = 6u << 20;                 // f32  [8192][64]  2 MiB
static constexpr size_t OFF_R    = 8u << 20;                 // f32  [8192][64]  2 MiB
static constexpr size_t OFF_PART = 10u << 20;                // bf16 [4][8192][256] 16 MiB
static constexpr size_t OFF_ZP   = 26u << 20;                // f32  [4][8192]   128 KiB
static constexpr size_t OFF_XB   = 27u << 20;                // bf16 [8192][256] 4 MiB

__device__ __forceinline__ float fast_exp2(float x) {
  float e;
  asm("v_exp_f32 %0, %1" : "=v"(e) : "v"(x));
  return e;
}

__device__ __forceinline__ bf16x8 cvt8(float4 a, float4 b) {
  bf16x8 o;
  o[0] = (__bf16)a.x; o[1] = (__bf16)a.y; o[2] = (__bf16)a.z; o[3] = (__bf16)a.w;
  o[4] = (__bf16)b.x; o[5] = (__bf16)b.y; o[6] = (__bf16)b.z; o[7] = (__bf16)b.w;
  return o;
}

// async global->LDS, 16B/lane; lds dst is the wave-uniform base (HW adds 16*lane).
__device__ __forceinline__ void gll16(const __bf16* g, __bf16* l) {
  __builtin_amdgcn_global_load_lds((const __attribute__((address_space(1))) void*)g,
                                   (__attribute__((address_space(3))) void*)l,
                                   16, 0, 0);
}

// ---------------- weight prep + x->bf16 (R13 version, verbatim)
__global__ __launch_bounds__(1024) void k_prepw(const float* __restrict__ Wv,
                                                const float* __restrict__ Wl,
                                                const float* __restrict__ Wr,
                                                const float* __restrict__ Wo,
                                                const float* __restrict__ x,
                                                __bf16* __restrict__ Wvt,
                                                __bf16* __restrict__ Wlt,
                                                __bf16* __restrict__ Wrt,
                                                __bf16* __restrict__ xb) {
  __shared__ float red[3][256];
  const int blk = blockIdx.x;
  const int t = threadIdx.x;
  if (blk < 32) {
    const int idx = blk * 1024 + t;              // 0 .. 32767
    if (idx < 16384) {
      const int k = idx >> 6, n = idx & 63;
      Wlt[n * 256 + k] = (__bf16)Wl[idx];
    } else {
      const int j = idx - 16384;
      const int k = j >> 6, n = j & 63;
      Wrt[n * 256 + k] = (__bf16)Wr[j];
    }
  } else if (blk < 288) {
    const int k  = blk - 32;                     // 0..255
    const int n  = t & 255;
    const int jq = t >> 8;                       // 0..3
    const float* wvr = Wv + (size_t)k * 256 + jq * 64;
    const float* wor = Wo + (size_t)(jq * 64) * 256 + n;
    float a0 = 0.f, a1 = 0.f, a2 = 0.f, a3 = 0.f;
#pragma unroll 4
    for (int j = 0; j < 64; j += 4) {
      a0 += wvr[j + 0] * wor[(size_t)(j + 0) * 256];
      a1 += wvr[j + 1] * wor[(size_t)(j + 1) * 256];
      a2 += wvr[j + 2] * wor[(size_t)(j + 2) * 256];
      a3 += wvr[j + 3] * wor[(size_t)(j + 3) * 256];
    }
    const float s = (a0 + a1) + (a2 + a3);
    if (jq > 0) red[jq - 1][n] = s;
    __syncthreads();
    if (jq == 0)
      Wvt[(size_t)n * 256 + k] = (__bf16)(s + red[0][n] + red[1][n] + red[2][n]);
  } else {
    const size_t base = (size_t)(blk - 288) * 8192 + (size_t)t * 8;
    float4 a = *(const float4*)(x + base);
    float4 b = *(const float4*)(x + base + 4);
    *(bf16x8*)(xb + base) = cvt8(a, b);
  }
}

// --------- projections (R13 version, verbatim): bf16 xb A-operands.
__global__ __launch_bounds__(256) void k_proj(const __bf16* __restrict__ xb,
                                              const __bf16* __restrict__ Wvt,
                                              const __bf16* __restrict__ Wlt,
                                              const __bf16* __restrict__ Wrt,
                                              __bf16* __restrict__ Vt,
                                              float* __restrict__ lbuf,
                                              float* __restrict__ rbuf) {
  __shared__ __align__(16) char smem[16896];       // V path: 8KB bf16; lr path: [64][65] f32
  const int t = threadIdx.x;
  const int lane = t & 63, wave = t >> 6;
  const int l16 = lane & 15, quad = lane >> 4;
  const int wr = wave >> 1, wc = wave & 1;
  const int bid = blockIdx.x;
  const int q   = bid / 48;
  const int rmd = bid - q * 48;
  const int ct  = rmd >> 3;
  const int rbk = q * 8 + (rmd & 7);
  const __bf16* Wt;
  int colbase;
  if (ct < 4)       { Wt = Wvt; colbase = ct * 64; }
  else if (ct == 4) { Wt = Wlt; colbase = 0; }
  else              { Wt = Wrt; colbase = 0; }
  const int row0 = rbk * 64 + wr * 32;
  const int c0   = colbase + wc * 32;
  f32x4 acc[2][2] = {};
  for (int kk = 0; kk < 256; kk += 32) {
    const int ko = kk + quad * 8;
    bf16x8 a0 = *(const bf16x8*)(xb + (size_t)(row0 + l16) * 256 + ko);
    bf16x8 a1 = *(const bf16x8*)(xb + (size_t)(row0 + 16 + l16) * 256 + ko);
    bf16x8 b0 = *(const bf16x8*)(Wt + (size_t)(c0 + l16) * 256 + ko);
    bf16x8 b1 = *(const bf16x8*)(Wt + (size_t)(c0 + 16 + l16) * 256 + ko);
    acc[0][0] = MFMA16(a0, b0, acc[0][0]);
    acc[0][1] = MFMA16(a0, b1, acc[0][1]);
    acc[1][0] = MFMA16(a1, b0, acc[1][0]);
    acc[1][1] = MFMA16(a1, b1, acc[1][1]);
  }
  if (ct < 4) {
    __bf16* vs = (__bf16*)smem;                  // [m8][d_local][j]
#pragma unroll
    for (int mt = 0; mt < 2; ++mt)
#pragma unroll
      for (int nt = 0; nt < 2; ++nt) {
        const int m8 = wr * 4 + mt * 2 + (quad >> 1);
        const int d  = wc * 32 + nt * 16 + l16;
        bf16x4 o;
        o.x = (__bf16)acc[mt][nt][0];
        o.y = (__bf16)acc[mt][nt][1];
        o.z = (__bf16)acc[mt][nt][2];
        o.w = (__bf16)acc[mt][nt][3];
        *(bf16x4*)(&vs[m8 * 512 + d * 8 + (quad & 1) * 4]) = o;
      }
    __syncthreads();
    const int m8 = t >> 5, s32 = t & 31;
    const int bat = rbk >> 6, mc = rbk & 63;
    bf16x8 a = *(const bf16x8*)(&vs[m8 * 512 + s32 * 16]);
    bf16x8 b = *(const bf16x8*)(&vs[m8 * 512 + s32 * 16 + 8]);
    __bf16* dst = Vt + (size_t)bat * 1048576 + (size_t)mc * 16384 +
                  m8 * 2048 + ct * 512 + s32 * 16;
    *(bf16x8*)dst       = a;
    *(bf16x8*)(dst + 8) = b;
  } else {
    float* lsf = (float*)smem;                   // [64][65]
#pragma unroll
    for (int mt = 0; mt < 2; ++mt)
#pragma unroll
      for (int nt = 0; nt < 2; ++nt) {
        const int col = wc * 32 + nt * 16 + l16;
        const int r0  = wr * 32 + mt * 16 + quad * 4;
#pragma unroll
        for (int rr = 0; rr < 4; ++rr)
          lsf[(r0 + rr) * 65 + col] = acc[mt][nt][rr];
      }
    __syncthreads();
    float* dstb = (ct == 4) ? lbuf : rbuf;
    const int row = t >> 2, cs = (t & 3) * 16;
    const float* src = lsf + row * 65 + cs;
    float* d = dstb + (size_t)(rbk * 64 + row) * 64 + cs;
#pragma unroll
    for (int v = 0; v < 4; ++v) {
      f32x4 o;
      o[0] = src[v * 4 + 0]; o[1] = src[v * 4 + 1];
      o[2] = src[v * 4 + 2]; o[3] = src[v * 4 + 3];
      *(f32x4*)(d + v * 4) = o;
    }
  }
}

// ---------------- main attention GEMM: R6 geometry (grid 512, TM=64, TN=256,
// split-K=4, 4-buffer vmcnt-12 pipeline, LDS 68.25 KB) with ONE change:
// waves split by ROW only (4 waves x 16 rows, nt=16 col-tiles each) instead
// of 2row x 2col. Kills the x2 exp duplication (R14 counters: VALU/trans is
// attn's heaviest pipe): 8 exps/thread/chunk (= exactly the unique count),
// rreg 32->16 VGPR. MFMA count/wave unchanged (16); ds_read doubles (LDS has
// headroom). STAGE/pipeline/barriers byte-identical to R6.
__global__ __launch_bounds__(256, 2) void k_attn(const float* __restrict__ lbuf,
                                                 const float* __restrict__ rbuf,
                                                 const __bf16* __restrict__ Vt,
                                                 __bf16* __restrict__ part,
                                                 float* __restrict__ zpart) {
  __shared__ __align__(16) char smem[69888];   // vb[4][16KB] + ls[64][17]f32; epi ctile aliases
  __bf16* vb0 = (__bf16*)smem;
  __bf16* vb1 = (__bf16*)(smem + 16384);
  __bf16* vb2 = (__bf16*)(smem + 32768);
  __bf16* vb3 = (__bf16*)(smem + 49152);
  float*  ls  = (float*)(smem + 65536);        // [64][17]
  const int t = threadIdx.x;                   // 0..255
  const int lane = t & 63, w = t >> 6;         // wave w owns rows w*16..+15
  const int l16 = lane & 15, quad = lane >> 4;
  const int bid = blockIdx.x;                  // 0..511
  const int cmb = bid & 7;
  const int sp  = cmb >> 1;                    // 0..3
  const int bat = cmb & 1;                     // 0..1
  const int rbl = bid >> 3;                    // 0..63
  const int g0  = bat * 4096 + rbl * 64;
  const __bf16* Vbase = Vt + (size_t)bat * 1048576;
  const int ck0 = sp * 32;                     // first K=32 chunk of this split

  // l tile: rows g0..+63, 16 chunk-cols (stride 17 -> conflict-free reads)
  {
    const int row = t >> 2, c = (t & 3) * 4;
    f32x4 v = *(const f32x4*)(lbuf + (size_t)(g0 + row) * 64 + sp * 16 + c);
    ls[row * 17 + c + 0] = v[0];
    ls[row * 17 + c + 1] = v[1];
    ls[row * 17 + c + 2] = v[2];
    ls[row * 17 + c + 3] = v[3];
  }
  // r fragments pre-scaled by log2(e): rreg[hf+j] = r[row][hf*4 + quad*8 + j]
  // (hf=0 -> k=quad*8+j ; hf=8 -> k=32+quad*8+j), row = g0 + w*16 + l16
  const float LOG2E = 1.44269504088896f;
  float rreg[16];
  {
    const float* rp = rbuf + (size_t)(g0 + w * 16 + l16) * 64;
    f32x4 a = *(const f32x4*)(rp + quad * 8);
    f32x4 b = *(const f32x4*)(rp + quad * 8 + 4);
    f32x4 c = *(const f32x4*)(rp + 32 + quad * 8);
    f32x4 d = *(const f32x4*)(rp + 32 + quad * 8 + 4);
#pragma unroll
    for (int j = 0; j < 4; ++j) {
      rreg[j]      = a[j] * LOG2E;
      rreg[4 + j]  = b[j] * LOG2E;
      rreg[8 + j]  = c[j] * LOG2E;
      rreg[12 + j] = d[j] * LOG2E;
    }
  }

  f32x4 acc[16] = {};
  float zacc[2] = {0.f, 0.f};

#define STAGE(KC, DST)                                                          \
  {                                                                             \
    const __bf16* src = Vbase + (size_t)(ck0 + (KC)) * 8192;                    \
    _Pragma("unroll")                                                           \
    for (int i = 0; i < 4; ++i)                                                 \
      gll16(src + (size_t)(i * 256 + t) * 8, (DST) + (i * 256 + (w << 6)) * 8); \
  }

#define AF_COMPUTE(KC)                                                        \
  {                                                                           \
    const int c16 = (KC) >> 1, hf = ((KC) & 1) * 8;                           \
    const float lv = ls[(w * 16 + l16) * 17 + c16];                           \
    _Pragma("unroll")                                                         \
    for (int j = 0; j < 8; ++j) {                                             \
      const float e = fast_exp2(lv * rreg[hf + j]);                           \
      zacc[(KC) & 1] += e;                                                    \
      af[j] = (__bf16)e;                                                      \
    }                                                                         \
  }

#define MFMA_PHASE(CUR)                                                       \
  {                                                                           \
    _Pragma("unroll")                                                         \
    for (int nt = 0; nt < 16; ++nt) {                                         \
      bf16x8 bv = *(const bf16x8*)((CUR) + quad * 2048 + (nt * 16 + l16) * 8);\
      acc[nt] = MFMA16(af, bv, acc[nt]);                                      \
    }                                                                         \
  }

#define STEP(CC, BCUR, SC, BST, VM)                                           \
  {                                                                           \
    STAGE(SC, BST);                                                           \
    bf16x8 af;                                                                \
    AF_COMPUTE(CC);                                                           \
    asm volatile("s_waitcnt vmcnt(" #VM ")" ::: "memory");                    \
    __builtin_amdgcn_s_barrier();                                             \
    __builtin_amdgcn_sched_barrier(0);                                        \
    MFMA_PHASE(BCUR);                                                         \
    __builtin_amdgcn_s_barrier();                                             \
    __builtin_amdgcn_sched_barrier(0);                                        \
  }

#define STEPX(CC, BCUR, VM)                                                   \
  {                                                                           \
    bf16x8 af;                                                                \
    AF_COMPUTE(CC);                                                           \
    asm volatile("s_waitcnt vmcnt(" #VM ")" ::: "memory");                    \
    __builtin_amdgcn_s_barrier();                                             \
    __builtin_amdgcn_sched_barrier(0);                                        \
    MFMA_PHASE(BCUR);                                                         \
    __builtin_amdgcn_s_barrier();                                             \
    __builtin_amdgcn_sched_barrier(0);                                        \
  }

  // prologue: chunks 0..2 staged; the only full drain in the loop
  STAGE(0, vb0);
  STAGE(1, vb1);
  STAGE(2, vb2);
  __syncthreads();

  // steady: chunk cc in buffer cc%4; prefetch distance 3 -> vmcnt(12)
  for (int c = 0; c < 28; c += 4) {
    STEP(c + 0, vb0, c + 3, vb3, 12);
    STEP(c + 1, vb1, c + 4, vb0, 12);
    STEP(c + 2, vb2, c + 5, vb1, 12);
    STEP(c + 3, vb3, c + 6, vb2, 12);
  }
  STEP (28, vb0, 31, vb3, 12);
  STEPX(29, vb1, 8);
  STEPX(30, vb2, 4);
  STEPX(31, vb3, 0);

#undef STAGE
#undef AF_COMPUTE
#undef MFMA_PHASE
#undef STEP
#undef STEPX

  // Z partials: each row owned by exactly one wave; reduce across quads.
  {
    float z = zacc[0] + zacc[1];
    z += __shfl_xor(z, 16);
    z += __shfl_xor(z, 32);
    if (quad == 0)
      zpart[(size_t)sp * 8192 + g0 + w * 16 + l16] = z;
  }

  // epilogue: stage C tile (64x256 bf16, stride 264) in LDS, coalesced 16B writes
  __syncthreads();                 // all LDS reads done before aliasing
  __bf16* ctile = (__bf16*)smem;
#pragma unroll
  for (int nt = 0; nt < 16; ++nt) {
    const int r0 = w * 16 + quad * 4;
    const int c  = nt * 16 + l16;
#pragma unroll
    for (int rr = 0; rr < 4; ++rr)
      ctile[(r0 + rr) * 264 + c] = (__bf16)acc[nt][rr];
  }
  __syncthreads();
  __bf16* pb = part + (size_t)sp * (8192 * 256);
#pragma unroll
  for (int p = 0; p < 8; ++p) {
    const int u = p * 256 + t;
    const int row = u >> 5, seg = u & 31;
    *(bf16x8*)(pb + (size_t)(g0 + row) * 256 + seg * 8) =
        *(const bf16x8*)(ctile + row * 264 + seg * 8);
  }
}

// ------- final fixup (R6 version): out = (sum_s part[s]) / Z  (pure streaming)
__global__ __launch_bounds__(256) void k_fix(const __bf16* __restrict__ part,
                                             const float* __restrict__ zpart,
                                             float* __restrict__ out) {
  const int idx = blockIdx.x * 256 + threadIdx.x;   // 0 .. 262143
  const int g = idx >> 5, seg = idx & 31;
  float z = 0.f;
#pragma unroll
  for (int s = 0; s < 4; ++s) z += zpart[(size_t)s * 8192 + g];
  const float iz = 1.0f / z;
  float sum[8] = {};
#pragma unroll
  for (int s = 0; s < 4; ++s) {
    bf16x8 p = *(const bf16x8*)(part + (size_t)s * (8192 * 256) + (size_t)g * 256 + seg * 8);
#pragma unroll
    for (int j = 0; j < 8; ++j) sum[j] += (float)p[j];
  }
  f32x4 o0, o1;
#pragma unroll
  for (int j = 0; j < 4; ++j) { o0[j] = sum[j] * iz; o1[j] = sum[4 + j] * iz; }
  float* dst = out + (size_t)g * 256 + seg * 8;
  *(f32x4*)dst       = o0;
  *(f32x4*)(dst + 4) = o1;
}

extern "C" void kernel_launch(void* const* d_in, const int* in_sizes, int n_in,
                              void* d_out, int out_size, void* d_ws, size_t ws_size,
                              hipStream_t stream) {
  const float* x  = (const float*)d_in[0];
  const float* Wl = (const float*)d_in[1];
  const float* Wr = (const float*)d_in[2];
  const float* Wv = (const float*)d_in[3];
  const float* Wo = (const float*)d_in[4];
  char* ws = (char*)d_ws;
  __bf16* Wvt = (__bf16*)(ws + OFF_WVT);
  __bf16* Wlt = (__bf16*)(ws + OFF_WLT);
  __bf16* Wrt = (__bf16*)(ws + OFF_WRT);
  __bf16* Vt  = (__bf16*)(ws + OFF_VT);
  float*  lb  = (float*)(ws + OFF_L);
  float*  rbf = (float*)(ws + OFF_R);
  __bf16* prt = (__bf16*)(ws + OFF_PART);
  float*  zp  = (float*)(ws + OFF_ZP);
  __bf16* xb  = (__bf16*)(ws + OFF_XB);
  float*  out = (float*)d_out;

  k_prepw<<<544, 1024, 0, stream>>>(Wv, Wl, Wr, Wo, x, Wvt, Wlt, Wrt, xb);
  k_proj<<<768, 256, 0, stream>>>(xb, Wvt, Wlt, Wrt, Vt, lb, rbf);
  k_attn<<<512, 256, 0, stream>>>(lb, rbf, Vt, prt, zp);
  k_fix<<<1024, 256, 0, stream>>>(prt, zp, out);
}